// Round 3
// baseline (462.313 us; speedup 1.0000x reference)
//
#include <hip/hip_runtime.h>

// LIF scan, speculative T-chunking + contiguous streaming layout.
// Block = (batch b, T-chunk k): 128 threads x float4 = all 512 channels.
// Each step is a contiguous 2KB block read/write; consecutive t adjacent.
// Chunks k>0 start Vm=0 at t0-W and run W warm-up steps (self-reset
// coalescing makes this exact w.h.p.); chunk 0 is exact by construction.

typedef float f4 __attribute__((ext_vector_type(4)));

constexpr int B = 128;
constexpr int T = 1000;
constexpr int C = 512;
constexpr int NCH = 8;
constexpr int CHUNK = 125;   // stored steps per chunk
constexpr int W = 75;        // warm-up steps (15 batches of U)
constexpr int U = 5;         // steps per batch (both 125 and 200 divisible)

__global__ __launch_bounds__(128) void lif_kernel(
    const float* __restrict__ x, const float* __restrict__ w_leak,
    float* __restrict__ out) {
#pragma clang fp contract(off)
  const int blk = blockIdx.x;
  const int b = blk >> 3;          // / NCH
  const int k = blk & (NCH - 1);   // % NCH
  const int c0 = threadIdx.x << 2; // 4 channels per thread

  const f4 wl = *reinterpret_cast<const f4*>(w_leak + c0);
  const float dxc = 1.0f - wl[0], dyc = 1.0f - wl[1],
              dzc = 1.0f - wl[2], dwc = 1.0f - wl[3];

  const int t0 = k * CHUNK;
  const int tb = (k == 0) ? 0 : (t0 - W);
  const int NB = (k == 0) ? (CHUNK / U) : ((CHUNK + W) / U); // 25 or 40
  const int nwarm = NB - CHUNK / U;                          // 0 or 15

  const float* xp = x + ((size_t)b * T + tb) * C + c0;
  float* op = out + ((size_t)b * T + t0) * C + c0;

  f4 bufA[U], bufB[U];
  float vx = 0.f, vy = 0.f, vz = 0.f, vw = 0.f;

#define LOADB(buf, j)                                                      \
  do {                                                                     \
    const float* p_ = xp + (size_t)(j) * (U * C);                          \
    _Pragma("unroll")                                                      \
    for (int u = 0; u < U; ++u)                                            \
      buf[u] = *reinterpret_cast<const f4*>(p_ + (size_t)u * C);           \
  } while (0)

#define STEP1(v, d, xv, sp)                                                \
  {                                                                        \
    float dv = (d) * (v);            /* one rounding, no FMA */            \
    dv = ((v) < 1.0f) ? dv : 0.0f;   /* hard-reset gate */                 \
    float s = (xv) + dv;             /* one rounding */                    \
    (v) = fmaxf(s, 0.0f);            /* relu */                            \
    (sp) = ((v) > 1.0f) ? 1.0f : 0.0f;                                     \
  }

#define COMPUTEB(buf, j)                                                   \
  do {                                                                     \
    const bool st_ = (j) >= nwarm;   /* uniform per block */               \
    float* q_ = op + (ptrdiff_t)((j) - nwarm) * (U * C);                   \
    _Pragma("unroll")                                                      \
    for (int u = 0; u < U; ++u) {                                          \
      f4 sp;                                                               \
      STEP1(vx, dxc, buf[u][0], sp[0]);                                    \
      STEP1(vy, dyc, buf[u][1], sp[1]);                                    \
      STEP1(vz, dzc, buf[u][2], sp[2]);                                    \
      STEP1(vw, dwc, buf[u][3], sp[3]);                                    \
      if (st_)                                                             \
        __builtin_nontemporal_store(                                       \
            sp, reinterpret_cast<f4*>(q_ + (size_t)u * C));                \
    }                                                                      \
  } while (0)

  LOADB(bufA, 0);
  LOADB(bufB, 1);

  int j = 0;
#pragma unroll 1
  for (; j + 2 <= NB; j += 2) {
    COMPUTEB(bufA, j);
    if (j + 2 < NB) LOADB(bufA, j + 2);
    COMPUTEB(bufB, j + 1);
    if (j + 3 < NB) LOADB(bufB, j + 3);
  }
  if (j < NB) COMPUTEB(bufA, j);   // NB=25 tail (even index -> bufA)

#undef LOADB
#undef STEP1
#undef COMPUTEB
}

extern "C" void kernel_launch(void* const* d_in, const int* in_sizes, int n_in,
                              void* d_out, int out_size, void* d_ws, size_t ws_size,
                              hipStream_t stream) {
  const float* x = (const float*)d_in[0];
  const float* w = (const float*)d_in[1];
  float* out = (float*)d_out;
  dim3 block(128);
  dim3 grid(B * NCH);   // 1024 blocks -> 2 waves/SIMD
  lif_kernel<<<grid, block, 0, stream>>>(x, w, out);
}

// Round 4
// 446.622 us; speedup vs baseline: 1.0351x; 1.0351x over previous
//
#include <hip/hip_runtime.h>

// LIF scan: thread per (b,c) chain (proven-exact layout), 2-way speculative
// T-split for 2 waves/SIMD, 25-deep double-buffered prefetch for ~13 MB
// chip-wide in flight (2.3x the HBM BW*latency product).

constexpr int B = 128;
constexpr int T = 1000;
constexpr int C = 512;
constexpr int HALF = 500;   // stored steps per chunk
constexpr int W = 75;       // warm-up steps for chunk 1 (validated in R3)
constexpr int U = 25;       // steps per load batch; 500=20*25, 575=23*25

__global__ __launch_bounds__(256) void lif_kernel(
    const float* __restrict__ x, const float* __restrict__ w_leak,
    float* __restrict__ out) {
#pragma clang fp contract(off)
  const int k = blockIdx.x >> 8;                       // T-chunk: 0 or 1
  const int gi = ((blockIdx.x & 255) << 8) | threadIdx.x;
  const int b = gi >> 9;          // / C
  const int c = gi & (C - 1);     // % C
  const float decay = 1.0f - w_leak[c];

  const int tb = (k == 0) ? 0 : (HALF - W);            // load start
  const int nb = (k == 0) ? (HALF / U) : ((HALF + W) / U);  // 20 or 23
  const int nwarm = nb - HALF / U;                     // 0 or 3

  const float* xp = x + ((size_t)b * T + tb) * C + c;
  float* op = out + ((size_t)b * T + (size_t)k * HALF) * C + c;

  float bufA[U], bufB[U];
  float Vm = 0.0f;

#define LOADB(buf, j)                                                      \
  do {                                                                     \
    const float* p_ = xp + (size_t)(j) * ((size_t)U * C);                  \
    _Pragma("unroll")                                                      \
    for (int u = 0; u < U; ++u) buf[u] = p_[(size_t)u * C];                \
  } while (0)

#define COMPUTEB(buf, j)                                                   \
  do {                                                                     \
    const bool st_ = (j) >= nwarm;   /* uniform per block */               \
    float* q_ = op + (ptrdiff_t)((j) - nwarm) * (U * C);                   \
    _Pragma("unroll")                                                      \
    for (int u = 0; u < U; ++u) {                                          \
      float dv = decay * Vm;               /* one rounding, no FMA */      \
      dv = (Vm < 1.0f) ? dv : 0.0f;        /* hard-reset gate */           \
      float s = buf[u] + dv;               /* one rounding */              \
      Vm = fmaxf(s, 0.0f);                 /* relu */                      \
      if (st_)                                                             \
        __builtin_nontemporal_store((Vm > 1.0f) ? 1.0f : 0.0f,             \
                                    q_ + (size_t)u * C);                   \
    }                                                                      \
  } while (0)

  LOADB(bufA, 0);
  LOADB(bufB, 1);

  int j = 0;
#pragma unroll 1
  for (; j + 2 <= nb; j += 2) {
    COMPUTEB(bufA, j);
    if (j + 2 < nb) LOADB(bufA, j + 2);
    COMPUTEB(bufB, j + 1);
    if (j + 3 < nb) LOADB(bufB, j + 3);
  }
  if (j < nb) COMPUTEB(bufA, j);   // odd-nb tail (nb=23 -> batch 22 in bufA)

#undef LOADB
#undef COMPUTEB
}

extern "C" void kernel_launch(void* const* d_in, const int* in_sizes, int n_in,
                              void* d_out, int out_size, void* d_ws, size_t ws_size,
                              hipStream_t stream) {
  const float* x = (const float*)d_in[0];
  const float* w = (const float*)d_in[1];
  float* out = (float*)d_out;
  dim3 block(256);
  dim3 grid((B * C) / 256 * 2);   // 512 blocks: chunk0 = blocks[0,256), chunk1 = [256,512)
  lif_kernel<<<grid, block, 0, stream>>>(x, w, out);
}